// Round 2
// baseline (106.634 us; speedup 1.0000x reference)
//
#include <hip/hip_runtime.h>

// Chamfer, B=4, N=M=8192 fp32 -> scalar. Round 5: MFMA rewrite.
// Round-4 post-mortem: VALU-issue saturated (VALUBusy ~110%, 83% of throttled VALU
// ceiling), MfmaUtil 0. Move the pairwise d2 = |p|^2 + |q|^2 - 2 p.q onto matrix cores:
// exact 3-way bf16 split per fp32 value; 8 product terms/coord (24 slots) + split |p|^2
// (3) + split |q|^2 (3) = 30 <= K=32 -> ONE mfma_f32_16x16x32_bf16 per 16x16 tile.
// All bf16 limb products are exact in fp32; only accumulation-order rounding (~5e-6/entry)
// differs from the fp32 reference. Direction-doubled matrices => row-mins complete per
// wave => no atomics, plain stores.
// Workspace: sArr 4MB + tArr 4MB + wmin 256KB = 8.25 MB.

#define BATCH 4
#define NPTS 8192
#define SETPTS (BATCH * NPTS)       // 32768
#define TOTPTS (2 * SETPTS)         // 65536
#define NSLOT 32                    // bf16 K-slots per point (30 used)
#define CHUNK_PTS 256               // col points staged per chunk = 16 tiles
#define NCHUNK (NPTS / CHUNK_PTS)   // 32
#define CHUNK_BYTES (CHUNK_PTS * NSLOT * 2)  // 16384

typedef __attribute__((ext_vector_type(8))) short bf16x8;
typedef __attribute__((ext_vector_type(4))) float f32x4;

__device__ __forceinline__ float bf16rn(float v) {  // round-to-nearest-even to bf16 value
  unsigned u = __float_as_uint(v);
  u = (u + 0x7FFFu + ((u >> 16) & 1u)) & 0xFFFF0000u;
  return __uint_as_float(u);
}
__device__ __forceinline__ unsigned short b2u(float v) {  // bf16 bits of a bf16-valued f32
  return (unsigned short)(__float_as_uint(v) >> 16);
}

// Per point: s-vec (row role, carries the -2 factor) and t-vec (col role):
//   coord d: s[8d+]: [-2a,-2a,-2a,-2b,-2b,-2b,-2c,-2c]   t[8d+]: [d,e,f,d,e,f,d,e]
//     -> pairs ad,ae,af,bd,be,bf,cd,ce (all limb products except ~2^-36 c*f)
//   slots 24-26: s = split(|p|^2), t = 1 ; slots 27-29: s = 1, t = split(|q|^2); 30-31: 0.
__global__ __launch_bounds__(256) void chamfer_prep_kernel(
    const float* __restrict__ p1, const float* __restrict__ p2,
    unsigned short* __restrict__ sArr, unsigned short* __restrict__ tArr,
    float* __restrict__ out) {
  const int i = blockIdx.x * 256 + threadIdx.x;  // 0..65535
  const float* src = (i < SETPTS) ? (p1 + 3 * (size_t)i) : (p2 + 3 * (size_t)(i - SETPTS));
  const float co[3] = {src[0], src[1], src[2]};
  union { unsigned short u[32]; uint4 v[4]; } sv, tv;
#pragma unroll
  for (int d = 0; d < 3; ++d) {
    const float v = co[d];
    const float a = bf16rn(v), r1 = v - a;        // Sterbenz-exact residuals
    const float bb = bf16rn(r1), r2 = r1 - bb;
    const float cc = bf16rn(r2);
    const unsigned short as = b2u(-2.f * a), bs = b2u(-2.f * bb), cs2 = b2u(-2.f * cc);
    const unsigned short at = b2u(a), bt = b2u(bb), ct = b2u(cc);
    sv.u[8 * d + 0] = as; sv.u[8 * d + 1] = as; sv.u[8 * d + 2] = as;
    sv.u[8 * d + 3] = bs; sv.u[8 * d + 4] = bs; sv.u[8 * d + 5] = bs;
    sv.u[8 * d + 6] = cs2; sv.u[8 * d + 7] = cs2;
    tv.u[8 * d + 0] = at; tv.u[8 * d + 1] = bt; tv.u[8 * d + 2] = ct;
    tv.u[8 * d + 3] = at; tv.u[8 * d + 4] = bt; tv.u[8 * d + 5] = ct;
    tv.u[8 * d + 6] = at; tv.u[8 * d + 7] = bt;
  }
  const float sp = fmaf(co[0], co[0], fmaf(co[1], co[1], co[2] * co[2]));
  const float g = bf16rn(sp), q1 = sp - g;
  const float h = bf16rn(q1), q2 = q1 - h;
  const float ii = bf16rn(q2);
  sv.u[24] = b2u(g); sv.u[25] = b2u(h); sv.u[26] = b2u(ii);
  tv.u[24] = 0x3F80; tv.u[25] = 0x3F80; tv.u[26] = 0x3F80;  // bf16(1.0)
  sv.u[27] = 0x3F80; sv.u[28] = 0x3F80; sv.u[29] = 0x3F80;
  tv.u[27] = b2u(g); tv.u[28] = b2u(h); tv.u[29] = b2u(ii);
  sv.u[30] = 0; sv.u[31] = 0; tv.u[30] = 0; tv.u[31] = 0;
  uint4* sd = (uint4*)(sArr + (size_t)i * NSLOT);
  uint4* td = (uint4*)(tArr + (size_t)i * NSLOT);
#pragma unroll
  for (int k = 0; k < 4; ++k) { sd[k] = sv.v[k]; td[k] = tv.v[k]; }
  if (i == 0) out[0] = 0.f;
}

// Block: 4 waves x 2 row-tiles = 128 rows, loops all 8192 cols (32 chunks x 16 tiles),
// double-buffered LDS staging via global_load_lds w=16 with pre-permuted global source
// (m173 pattern): LDS slot s holds (jt=s>>6, qr=(s>>4)&3, pt=s&15) so the reader's
// ds_read_b128 at lane*16 is linear (conflict-free) AND is exactly the B-fragment
// (col = lane&15, k-quarter = lane>>4). A-frag same layout, loaded straight from global.
__global__ __launch_bounds__(256) void chamfer_mfma_kernel(
    const unsigned short* __restrict__ sArr, const unsigned short* __restrict__ tArr,
    float* __restrict__ wmin) {
  const int bx = blockIdx.x;
  const int dirb = bx & 7;   // bx%8 -> XCD-aligned: each XCD's L2 sees one dirb's 512KB t-set
  const int rblk = bx >> 3;  // 0..63
  const int dir = dirb >> 2, b = dirb & 3;
  const unsigned short* sb = sArr + (size_t)((dir ? SETPTS : 0) + b * NPTS) * NSLOT;
  const unsigned short* tb = tArr + (size_t)((dir ? 0 : SETPTS) + b * NPTS) * NSLOT;
  float* wm = wmin + (size_t)dirb * NPTS;

  const int t = threadIdx.x;
  const int lane = t & 63, wid = t >> 6;
  const int l15 = lane & 15, l4 = lane >> 4;

  __shared__ uint4 sbuf[2][CHUNK_BYTES / 16];  // 2 x 16 KB
  char* cs = (char*)sbuf;

  const int rowbase = rblk * 128 + wid * 32;
  const bf16x8 a0 = *(const bf16x8*)(sb + (size_t)(rowbase + l15) * NSLOT + l4 * 8);
  const bf16x8 a1 = *(const bf16x8*)(sb + (size_t)(rowbase + 16 + l15) * NSLOT + l4 * 8);

  const char* gsrc[4];
#pragma unroll
  for (int k = 0; k < 4; ++k) {
    const int s = k * 256 + t;
    const int jt = s >> 6, qr = (s >> 4) & 3, pt = s & 15;
    gsrc[k] = (const char*)(tb + (size_t)(jt * 16 + pt) * NSLOT + qr * 8);
  }

  f32x4 acc0 = {INFINITY, INFINITY, INFINITY, INFINITY};
  f32x4 acc1 = acc0;
  const f32x4 zero = {0.f, 0.f, 0.f, 0.f};

#pragma unroll
  for (int k = 0; k < 4; ++k)
    __builtin_amdgcn_global_load_lds(
        (const __attribute__((address_space(1))) void*)gsrc[k],
        (__attribute__((address_space(3))) void*)(cs + (k * 256 + t) * 16), 16, 0, 0);
  __syncthreads();

  int cur = 0;
  for (int c = 0; c < NCHUNK; ++c) {
    if (c + 1 < NCHUNK) {  // prefetch next chunk into the other buffer
#pragma unroll
      for (int k = 0; k < 4; ++k)
        __builtin_amdgcn_global_load_lds(
            (const __attribute__((address_space(1))) void*)(gsrc[k] + (size_t)(c + 1) * CHUNK_BYTES),
            (__attribute__((address_space(3))) void*)(cs + (cur ^ 1) * CHUNK_BYTES + (k * 256 + t) * 16),
            16, 0, 0);
    }
    const char* bbase = cs + cur * CHUNK_BYTES + lane * 16;
#pragma unroll
    for (int jt = 0; jt < 16; ++jt) {
      const bf16x8 bf = *(const bf16x8*)(bbase + jt * 1024);  // linear ds_read_b128
      const f32x4 d0 = __builtin_amdgcn_mfma_f32_16x16x32_bf16(a0, bf, zero, 0, 0, 0);
      const f32x4 d1 = __builtin_amdgcn_mfma_f32_16x16x32_bf16(a1, bf, zero, 0, 0, 0);
#pragma unroll
      for (int r = 0; r < 4; ++r) {
        acc0[r] = fminf(acc0[r], d0[r]);  // C/D: col=lane&15, row=(lane>>4)*4+r [m89]
        acc1[r] = fminf(acc1[r], d1[r]);
      }
    }
    __syncthreads();  // implicit vmcnt(0): next buffer staged; cur safe to overwrite
    cur ^= 1;
  }

  // fold the 16 col-lanes (same lane>>4 group) -> complete row-mins
#pragma unroll
  for (int m = 1; m <= 8; m <<= 1) {
#pragma unroll
    for (int r = 0; r < 4; ++r) {
      acc0[r] = fminf(acc0[r], __shfl_xor(acc0[r], m, 64));
      acc1[r] = fminf(acc1[r], __shfl_xor(acc1[r], m, 64));
    }
  }
  if (l15 == 0) {
#pragma unroll
    for (int r = 0; r < 4; ++r) {
      wm[rowbase + l4 * 4 + r] = acc0[r];       // no clamp: match reference exactly
      wm[rowbase + 16 + l4 * 4 + r] = acc1[r];
    }
  }
}

__global__ __launch_bounds__(256) void chamfer_reduce_kernel(const float* __restrict__ wmin,
                                                             float* __restrict__ out) {
  // 65536 floats; 64 blocks x 256 threads x 4 elems
  float s = 0.f;
  const int base = blockIdx.x * 1024 + threadIdx.x;
#pragma unroll
  for (int k = 0; k < 4; ++k) s += wmin[base + k * 256];
#pragma unroll
  for (int off = 32; off > 0; off >>= 1) s += __shfl_down(s, off, 64);
  __shared__ float wsum[4];
  const int lane = threadIdx.x & 63, wid = threadIdx.x >> 6;
  if (lane == 0) wsum[wid] = s;
  __syncthreads();
  if (threadIdx.x == 0) atomicAdd(out, wsum[0] + wsum[1] + wsum[2] + wsum[3]);
}

extern "C" void kernel_launch(void* const* d_in, const int* in_sizes, int n_in,
                              void* d_out, int out_size, void* d_ws, size_t ws_size,
                              hipStream_t stream) {
  const float* p1 = (const float*)d_in[0];
  const float* p2 = (const float*)d_in[1];
  float* out = (float*)d_out;
  unsigned short* sArr = (unsigned short*)d_ws;                       // 4 MB
  unsigned short* tArr = (unsigned short*)((char*)d_ws + (4 << 20));  // 4 MB
  float* wmin = (float*)((char*)d_ws + (8 << 20));                    // 256 KB

  chamfer_prep_kernel<<<dim3(TOTPTS / 256), dim3(256), 0, stream>>>(p1, p2, sArr, tArr, out);
  chamfer_mfma_kernel<<<dim3(512), dim3(256), 0, stream>>>(sArr, tArr, wmin);
  chamfer_reduce_kernel<<<dim3(64), dim3(256), 0, stream>>>(wmin, out);
}

// Round 3
// 93.279 us; speedup vs baseline: 1.1432x; 1.1432x over previous
//
#include <hip/hip_runtime.h>

// Chamfer, B=4, N=M=8192 fp32 -> scalar. Round 6: feed the MFMA pipe.
// Round-5 post-mortem: 2 blocks/CU (occupancy 17%), VALUBusy 49% > MfmaUtil 26% --
// the per-element fmin chain and 2-MFMA-per-ds_read structure starved the matrix pipe.
// Fixes: (1) min3 over col-tile PAIRS: acc = min3(acc, dA, dB) halves min-VALU;
// (2) 4 row-tiles/wave: 1 ds_read_b128 feeds 4 MFMAs (LDS pipe 15 -> 7.5 us);
// (3) col-split x4 + clamped-uint atomicMin (round-4-validated): 1024 blocks = 4/CU,
//     16 waves/CU. Chip-wide pipe loads: MFMA 16.6 us (dominant), DS 7.5, VALU-min 3.4.

#define BATCH 4
#define NPTS 8192
#define SETPTS (BATCH * NPTS)       // 32768
#define TOTPTS (2 * SETPTS)         // 65536
#define NSLOT 32                    // bf16 K-slots per point (30 used)
#define CHUNK_PTS 256               // col points staged per chunk = 16 tiles
#define NCHUNK (NPTS / CHUNK_PTS)   // 32
#define CSPLIT 4                    // col-splits per (dirb, rowblock)
#define CHUNKS_PER (NCHUNK / CSPLIT)             // 8 chunks per block
#define CHUNK_BYTES (CHUNK_PTS * NSLOT * 2)      // 16384

typedef __attribute__((ext_vector_type(8))) short bf16x8;
typedef __attribute__((ext_vector_type(4))) float f32x4;

__device__ __forceinline__ float bf16rn(float v) {  // round-to-nearest-even to bf16 value
  unsigned u = __float_as_uint(v);
  u = (u + 0x7FFFu + ((u >> 16) & 1u)) & 0xFFFF0000u;
  return __uint_as_float(u);
}
__device__ __forceinline__ unsigned short b2u(float v) {  // bf16 bits of a bf16-valued f32
  return (unsigned short)(__float_as_uint(v) >> 16);
}

// Per point: s-vec (row role, carries the -2 factor) and t-vec (col role):
//   coord d: s[8d+]: [-2a,-2a,-2a,-2b,-2b,-2b,-2c,-2c]   t[8d+]: [d,e,f,d,e,f,d,e]
//     -> limb pairs ad,ae,af,bd,be,bf,cd,ce (drops only ~2^-36 c*f)
//   slots 24-26: s = split(|p|^2), t = 1 ; slots 27-29: s = 1, t = split(|q|^2); 30-31: 0.
__global__ __launch_bounds__(256) void chamfer_prep_kernel(
    const float* __restrict__ p1, const float* __restrict__ p2,
    unsigned short* __restrict__ sArr, unsigned short* __restrict__ tArr,
    unsigned int* __restrict__ wmin, float* __restrict__ out) {
  const int i = blockIdx.x * 256 + threadIdx.x;  // 0..65535
  const float* src = (i < SETPTS) ? (p1 + 3 * (size_t)i) : (p2 + 3 * (size_t)(i - SETPTS));
  const float co[3] = {src[0], src[1], src[2]};
  union { unsigned short u[32]; uint4 v[4]; } sv, tv;
#pragma unroll
  for (int d = 0; d < 3; ++d) {
    const float v = co[d];
    const float a = bf16rn(v), r1 = v - a;        // Sterbenz-exact residuals
    const float bb = bf16rn(r1), r2 = r1 - bb;
    const float cc = bf16rn(r2);
    const unsigned short as = b2u(-2.f * a), bs = b2u(-2.f * bb), cs2 = b2u(-2.f * cc);
    const unsigned short at = b2u(a), bt = b2u(bb), ct = b2u(cc);
    sv.u[8 * d + 0] = as; sv.u[8 * d + 1] = as; sv.u[8 * d + 2] = as;
    sv.u[8 * d + 3] = bs; sv.u[8 * d + 4] = bs; sv.u[8 * d + 5] = bs;
    sv.u[8 * d + 6] = cs2; sv.u[8 * d + 7] = cs2;
    tv.u[8 * d + 0] = at; tv.u[8 * d + 1] = bt; tv.u[8 * d + 2] = ct;
    tv.u[8 * d + 3] = at; tv.u[8 * d + 4] = bt; tv.u[8 * d + 5] = ct;
    tv.u[8 * d + 6] = at; tv.u[8 * d + 7] = bt;
  }
  const float sp = fmaf(co[0], co[0], fmaf(co[1], co[1], co[2] * co[2]));
  const float g = bf16rn(sp), q1 = sp - g;
  const float h = bf16rn(q1), q2 = q1 - h;
  const float ii = bf16rn(q2);
  sv.u[24] = b2u(g); sv.u[25] = b2u(h); sv.u[26] = b2u(ii);
  tv.u[24] = 0x3F80; tv.u[25] = 0x3F80; tv.u[26] = 0x3F80;  // bf16(1.0)
  sv.u[27] = 0x3F80; sv.u[28] = 0x3F80; sv.u[29] = 0x3F80;
  tv.u[27] = b2u(g); tv.u[28] = b2u(h); tv.u[29] = b2u(ii);
  sv.u[30] = 0; sv.u[31] = 0; tv.u[30] = 0; tv.u[31] = 0;
  uint4* sd = (uint4*)(sArr + (size_t)i * NSLOT);
  uint4* td = (uint4*)(tArr + (size_t)i * NSLOT);
#pragma unroll
  for (int k = 0; k < 4; ++k) { sd[k] = sv.v[k]; td[k] = tv.v[k]; }
  wmin[i] = 0x7F800000u;  // +inf bits: > any clamped finite float's bits
  if (i == 0) out[0] = 0.f;
}

// Block: 4 waves x 4 row-tiles = 256 rows, 8 chunks (2048 cols) of its col-split.
// LDS staging via global_load_lds w=16 with pre-permuted global source (m173): LDS slot
// s holds (jt=s>>6, qr=(s>>4)&3, pt=s&15) so ds_read_b128 at lane*16 is linear
// (conflict-free) and is exactly the B-fragment (col=lane&15, k-quarter=lane>>4).
__global__ __launch_bounds__(256, 4) void chamfer_mfma_kernel(
    const unsigned short* __restrict__ sArr, const unsigned short* __restrict__ tArr,
    unsigned int* __restrict__ wmin) {
  const int bx = blockIdx.x;
  const int dirb = bx & 7;         // bx%8 -> XCD-aligned: per-XCD L2 sees one dirb's t-set
  const int rblk = (bx >> 3) & 31; // 0..31 (256 rows each)
  const int csp = bx >> 8;         // 0..3 (2048 cols each)
  const int dir = dirb >> 2, b = dirb & 3;
  const unsigned short* sb = sArr + (size_t)((dir ? SETPTS : 0) + b * NPTS) * NSLOT;
  const unsigned short* tb = tArr + (size_t)((dir ? 0 : SETPTS) + b * NPTS) * NSLOT;
  unsigned int* wm = wmin + (size_t)dirb * NPTS;

  const int t = threadIdx.x;
  const int lane = t & 63, wid = t >> 6;
  const int l15 = lane & 15, l4 = lane >> 4;

  __shared__ uint4 sbuf[2][CHUNK_BYTES / 16];  // 2 x 16 KB
  char* cs = (char*)sbuf;

  const int rowbase = rblk * 256 + wid * 64;   // wave owns 64 rows = 4 row-tiles
  bf16x8 a0, a1, a2, a3;
  a0 = *(const bf16x8*)(sb + (size_t)(rowbase + 0 * 16 + l15) * NSLOT + l4 * 8);
  a1 = *(const bf16x8*)(sb + (size_t)(rowbase + 1 * 16 + l15) * NSLOT + l4 * 8);
  a2 = *(const bf16x8*)(sb + (size_t)(rowbase + 2 * 16 + l15) * NSLOT + l4 * 8);
  a3 = *(const bf16x8*)(sb + (size_t)(rowbase + 3 * 16 + l15) * NSLOT + l4 * 8);

  const char* gsrc[4];
#pragma unroll
  for (int k = 0; k < 4; ++k) {
    const int s = k * 256 + t;
    const int jt = s >> 6, qr = (s >> 4) & 3, pt = s & 15;
    gsrc[k] = (const char*)(tb + (size_t)(csp * (CHUNKS_PER * CHUNK_PTS) + jt * 16 + pt) * NSLOT + qr * 8);
  }

  f32x4 acc0 = {INFINITY, INFINITY, INFINITY, INFINITY};
  f32x4 acc1 = acc0, acc2 = acc0, acc3 = acc0;
  const f32x4 zero = {0.f, 0.f, 0.f, 0.f};

#pragma unroll
  for (int k = 0; k < 4; ++k)
    __builtin_amdgcn_global_load_lds(
        (const __attribute__((address_space(1))) void*)gsrc[k],
        (__attribute__((address_space(3))) void*)(cs + (k * 256 + t) * 16), 16, 0, 0);
  __syncthreads();

  int cur = 0;
  for (int c = 0; c < CHUNKS_PER; ++c) {
    if (c + 1 < CHUNKS_PER) {  // prefetch next chunk into the other buffer
#pragma unroll
      for (int k = 0; k < 4; ++k)
        __builtin_amdgcn_global_load_lds(
            (const __attribute__((address_space(1))) void*)(gsrc[k] + (size_t)(c + 1) * CHUNK_BYTES),
            (__attribute__((address_space(3))) void*)(cs + (cur ^ 1) * CHUNK_BYTES + (k * 256 + t) * 16),
            16, 0, 0);
    }
    const char* bbase = cs + cur * CHUNK_BYTES + lane * 16;
#pragma unroll
    for (int jt = 0; jt < 16; jt += 2) {  // col-tile PAIRS: min3 folds two results/op
      const bf16x8 bfA = *(const bf16x8*)(bbase + jt * 1024);        // linear ds_read_b128
      const bf16x8 bfB = *(const bf16x8*)(bbase + (jt + 1) * 1024);
      const f32x4 dA0 = __builtin_amdgcn_mfma_f32_16x16x32_bf16(a0, bfA, zero, 0, 0, 0);
      const f32x4 dB0 = __builtin_amdgcn_mfma_f32_16x16x32_bf16(a0, bfB, zero, 0, 0, 0);
      const f32x4 dA1 = __builtin_amdgcn_mfma_f32_16x16x32_bf16(a1, bfA, zero, 0, 0, 0);
      const f32x4 dB1 = __builtin_amdgcn_mfma_f32_16x16x32_bf16(a1, bfB, zero, 0, 0, 0);
      const f32x4 dA2 = __builtin_amdgcn_mfma_f32_16x16x32_bf16(a2, bfA, zero, 0, 0, 0);
      const f32x4 dB2 = __builtin_amdgcn_mfma_f32_16x16x32_bf16(a2, bfB, zero, 0, 0, 0);
      const f32x4 dA3 = __builtin_amdgcn_mfma_f32_16x16x32_bf16(a3, bfA, zero, 0, 0, 0);
      const f32x4 dB3 = __builtin_amdgcn_mfma_f32_16x16x32_bf16(a3, bfB, zero, 0, 0, 0);
#pragma unroll
      for (int r = 0; r < 4; ++r) {
        acc0[r] = fminf(fminf(acc0[r], dA0[r]), dB0[r]);  // v_min3_f32
        acc1[r] = fminf(fminf(acc1[r], dA1[r]), dB1[r]);
        acc2[r] = fminf(fminf(acc2[r], dA2[r]), dB2[r]);
        acc3[r] = fminf(fminf(acc3[r], dA3[r]), dB3[r]);
      }
    }
    __syncthreads();  // implicit vmcnt(0): next buffer staged; cur safe to overwrite
    cur ^= 1;
  }

  // fold the 16 col-lanes (same lane>>4 group) -> this block's row-mins
#pragma unroll
  for (int m = 1; m <= 8; m <<= 1) {
#pragma unroll
    for (int r = 0; r < 4; ++r) {
      acc0[r] = fminf(acc0[r], __shfl_xor(acc0[r], m, 64));
      acc1[r] = fminf(acc1[r], __shfl_xor(acc1[r], m, 64));
      acc2[r] = fminf(acc2[r], __shfl_xor(acc2[r], m, 64));
      acc3[r] = fminf(acc3[r], __shfl_xor(acc3[r], m, 64));
    }
  }
  if (l15 == 0) {  // C/D: col=lane&15, row=(lane>>4)*4+r [m89]
#pragma unroll
    for (int r = 0; r < 4; ++r) {
      atomicMin(&wm[rowbase + 0 * 16 + l4 * 4 + r], __float_as_uint(fmaxf(acc0[r], 0.f)));
      atomicMin(&wm[rowbase + 1 * 16 + l4 * 4 + r], __float_as_uint(fmaxf(acc1[r], 0.f)));
      atomicMin(&wm[rowbase + 2 * 16 + l4 * 4 + r], __float_as_uint(fmaxf(acc2[r], 0.f)));
      atomicMin(&wm[rowbase + 3 * 16 + l4 * 4 + r], __float_as_uint(fmaxf(acc3[r], 0.f)));
    }
  }
}

__global__ __launch_bounds__(256) void chamfer_reduce_kernel(const unsigned int* __restrict__ wmin,
                                                             float* __restrict__ out) {
  // 65536 elements; 64 blocks x 256 threads x 4 elems
  float s = 0.f;
  const int base = blockIdx.x * 1024 + threadIdx.x;
#pragma unroll
  for (int k = 0; k < 4; ++k) s += __uint_as_float(wmin[base + k * 256]);
#pragma unroll
  for (int off = 32; off > 0; off >>= 1) s += __shfl_down(s, off, 64);
  __shared__ float wsum[4];
  const int lane = threadIdx.x & 63, wid = threadIdx.x >> 6;
  if (lane == 0) wsum[wid] = s;
  __syncthreads();
  if (threadIdx.x == 0) atomicAdd(out, wsum[0] + wsum[1] + wsum[2] + wsum[3]);
}

extern "C" void kernel_launch(void* const* d_in, const int* in_sizes, int n_in,
                              void* d_out, int out_size, void* d_ws, size_t ws_size,
                              hipStream_t stream) {
  const float* p1 = (const float*)d_in[0];
  const float* p2 = (const float*)d_in[1];
  float* out = (float*)d_out;
  unsigned short* sArr = (unsigned short*)d_ws;                       // 4 MB
  unsigned short* tArr = (unsigned short*)((char*)d_ws + (4 << 20));  // 4 MB
  unsigned int* wmin = (unsigned int*)((char*)d_ws + (8 << 20));      // 256 KB

  chamfer_prep_kernel<<<dim3(TOTPTS / 256), dim3(256), 0, stream>>>(p1, p2, sArr, tArr, wmin, out);
  chamfer_mfma_kernel<<<dim3(8 * 32 * CSPLIT), dim3(256), 0, stream>>>(sArr, tArr, wmin);
  chamfer_reduce_kernel<<<dim3(64), dim3(256), 0, stream>>>(wmin, out);
}